// Round 8
// baseline (30.493 us; speedup 1.0000x reference)
//
#include <hip/hip_runtime.h>

#define BATCH   16384
#define DIM     1024
#define NLAYERS 4
#define NF4     (DIM / 4)     // 256 float4 per row
#define THREADS 256           // 4 waves per block
#define NBLOCKS 512           // 2048 waves x 8 rows = 16384 rows
#define ROWS    8             // rows per wave, depth-2 rolling prefetch

typedef float floatx4 __attribute__((ext_vector_type(4)));

// x_L = alpha * x0 + bsum;  alpha = 1 + sum_l s_l,
// s_l = alpha_l * (x0 . W[l]) + c_l,  c_l = (sum_{k<l} b[k]) . W[l].
// Streaming pipeline: each wave owns 8 rows; loads for row k+2 issue while
// row k is reduced/stored, so reads and writes are mixed in time machine-wide
// (breaks the R5/R7 read-phase/write-phase lockstep that capped us at ~5 TB/s).
__global__ __launch_bounds__(THREADS) void crossnet_kernel(
    const float* __restrict__ x0,
    const float* __restrict__ W,
    const float* __restrict__ b,
    float* __restrict__ out)
{
    __shared__ float4 lW[NLAYERS * NF4];   // 16384 B staged W
    __shared__ float4 lBsum[NF4];          //  4096 B (first 12 floats double as scratch)

    const int tid  = threadIdx.x;
    const int lane = tid & 63;
    const int wv   = tid >> 6;

    const int    gw   = blockIdx.x * (THREADS / 64) + wv;   // 0..2047
    const size_t base = (size_t)gw * ROWS;

    const float4* xbase = reinterpret_cast<const float4*>(x0) + base * NF4 + lane;
    floatx4*      obase = reinterpret_cast<floatx4*>(out)     + base * NF4 + lane;

    // ---- start the read stream immediately: rows 0 and 1 ----
    float4 X[3][4];                        // rolling buffer; indices static after unroll
#pragma unroll
    for (int j = 0; j < 4; ++j) X[0][j] = xbase[0 * NF4 + j * 64];
#pragma unroll
    for (int j = 0; j < 4; ++j) X[1][j] = xbase[1 * NF4 + j * 64];

    const float4* Wv = reinterpret_cast<const float4*>(W);
    const float4* bv = reinterpret_cast<const float4*>(b);

    // ---- prologue: stage W, build bsum and c_l constants ----
#pragma unroll
    for (int i = 0; i < NLAYERS * NF4 / THREADS; ++i)
        lW[tid + i * THREADS] = Wv[tid + i * THREADS];

    float4 b0 = bv[0 * NF4 + tid];
    float4 b1 = bv[1 * NF4 + tid];
    float4 b2 = bv[2 * NF4 + tid];
    float4 b3 = bv[3 * NF4 + tid];
    float4 w1 = Wv[1 * NF4 + tid];
    float4 w2 = Wv[2 * NF4 + tid];
    float4 w3 = Wv[3 * NF4 + tid];

    float4 pre = b0;
    float c1 = pre.x * w1.x + pre.y * w1.y + pre.z * w1.z + pre.w * w1.w;
    pre.x += b1.x; pre.y += b1.y; pre.z += b1.z; pre.w += b1.w;
    float c2 = pre.x * w2.x + pre.y * w2.y + pre.z * w2.z + pre.w * w2.w;
    pre.x += b2.x; pre.y += b2.y; pre.z += b2.z; pre.w += b2.w;
    float c3 = pre.x * w3.x + pre.y * w3.y + pre.z * w3.z + pre.w * w3.w;
    pre.x += b3.x; pre.y += b3.y; pre.z += b3.z; pre.w += b3.w;

#pragma unroll
    for (int off = 32; off; off >>= 1) {
        c1 += __shfl_xor(c1, off, 64);
        c2 += __shfl_xor(c2, off, 64);
        c3 += __shfl_xor(c3, off, 64);
    }
    float* scratch = reinterpret_cast<float*>(lBsum);   // overlay, pre-lBsum
    if (lane == 0) { scratch[wv] = c1; scratch[4 + wv] = c2; scratch[8 + wv] = c3; }
    __syncthreads();
    const float cp1 = scratch[0] + scratch[1] + scratch[2]  + scratch[3];
    const float cp2 = scratch[4] + scratch[5] + scratch[6]  + scratch[7];
    const float cp3 = scratch[8] + scratch[9] + scratch[10] + scratch[11];
    __syncthreads();                    // scratch reads done before overwrite
    lBsum[tid] = pre;
    __syncthreads();

    float4 bs[4];
#pragma unroll
    for (int j = 0; j < 4; ++j) bs[j] = lBsum[j * 64 + lane];

    // ---- pipelined row loop: prefetch k+2, compute k, store k ----
#pragma unroll
    for (int k = 0; k < ROWS; ++k) {
        if (k + 2 < ROWS) {
#pragma unroll
            for (int j = 0; j < 4; ++j)
                X[(k + 2) % 3][j] = xbase[(size_t)(k + 2) * NF4 + j * 64];
        }

        float d0 = 0.f, d1 = 0.f, d2 = 0.f, d3 = 0.f;
#pragma unroll
        for (int j = 0; j < 4; ++j) {
            const int fi = j * 64 + lane;
            const float4 xx = X[k % 3][j];
            const float4 a0 = lW[0 * NF4 + fi];
            const float4 a1 = lW[1 * NF4 + fi];
            const float4 a2 = lW[2 * NF4 + fi];
            const float4 a3 = lW[3 * NF4 + fi];
            d0 += xx.x * a0.x + xx.y * a0.y + xx.z * a0.z + xx.w * a0.w;
            d1 += xx.x * a1.x + xx.y * a1.y + xx.z * a1.z + xx.w * a1.w;
            d2 += xx.x * a2.x + xx.y * a2.y + xx.z * a2.z + xx.w * a2.w;
            d3 += xx.x * a3.x + xx.y * a3.y + xx.z * a3.z + xx.w * a3.w;
        }
#pragma unroll
        for (int off = 32; off; off >>= 1) {
            d0 += __shfl_xor(d0, off, 64);
            d1 += __shfl_xor(d1, off, 64);
            d2 += __shfl_xor(d2, off, 64);
            d3 += __shfl_xor(d3, off, 64);
        }

        float al = 1.0f;
        { float s = al * d0;            al += s;
          s = fmaf(al, d1, cp1);        al += s;
          s = fmaf(al, d2, cp2);        al += s;
          s = fmaf(al, d3, cp3);        al += s; }

#pragma unroll
        for (int j = 0; j < 4; ++j) {
            const float4 xx = X[k % 3][j];
            floatx4 o;
            o.x = fmaf(al, xx.x, bs[j].x);
            o.y = fmaf(al, xx.y, bs[j].y);
            o.z = fmaf(al, xx.z, bs[j].z);
            o.w = fmaf(al, xx.w, bs[j].w);
            __builtin_nontemporal_store(o, &obase[(size_t)k * NF4 + j * 64]);
        }
    }
}

extern "C" void kernel_launch(void* const* d_in, const int* in_sizes, int n_in,
                              void* d_out, int out_size, void* d_ws, size_t ws_size,
                              hipStream_t stream) {
    const float* x0 = (const float*)d_in[0];
    const float* W  = (const float*)d_in[1];
    const float* b  = (const float*)d_in[2];
    float* out      = (float*)d_out;

    crossnet_kernel<<<NBLOCKS, THREADS, 0, stream>>>(x0, W, b, out);
}

// Round 9
// 26.107 us; speedup vs baseline: 1.1680x; 1.1680x over previous
//
#include <hip/hip_runtime.h>

#define BATCH   16384
#define DIM     1024
#define NLAYERS 4
#define NF4     (DIM / 4)     // 256 float4 per row
#define THREADS 256           // 4 waves per block
#define NBLOCKS 2048          // 8192 waves x 2 rows = 16384 rows

typedef float floatx4 __attribute__((ext_vector_type(4)));

// x_L = alpha * x0 + bsum;  alpha = 1 + sum_l s_l,
// s_l = alpha_l * (x0 . W[l]) + c_l,  c_l = (sum_{k<l} b[k]) . W[l].
// R5's interleaved dual-row structure (best: 25.75us) + x-loads hoisted
// ABOVE the prologue (latency hides under W/b staging + reduce) + exact
// 20480 B LDS (8 blocks/CU, single co-resident generation).
__global__ __launch_bounds__(THREADS) void crossnet_kernel(
    const float* __restrict__ x0,
    const float* __restrict__ W,
    const float* __restrict__ b,
    float* __restrict__ out)
{
    __shared__ float4 lW[NLAYERS * NF4];   // 16384 B staged W
    __shared__ float4 lBsum[NF4];          //  4096 B (first 12 floats double as scratch)

    const int tid  = threadIdx.x;
    const int lane = tid & 63;
    const int wv   = tid >> 6;

    // ---- issue BOTH rows' stream loads before any prologue work ----
    const int gw = blockIdx.x * (THREADS / 64) + wv;   // 0..8191
    const size_t r0 = (size_t)(2 * gw);
    const size_t r1 = r0 + 1;
    const float4* xa = reinterpret_cast<const float4*>(x0) + r0 * NF4;
    const float4* xb = reinterpret_cast<const float4*>(x0) + r1 * NF4;

    float4 A[4], B[4];
#pragma unroll
    for (int j = 0; j < 4; ++j) A[j] = xa[j * 64 + lane];
#pragma unroll
    for (int j = 0; j < 4; ++j) B[j] = xb[j * 64 + lane];

    const float4* Wv = reinterpret_cast<const float4*>(W);
    const float4* bv = reinterpret_cast<const float4*>(b);

    // ---- prologue: stage W, build bsum and c_l constants ----
#pragma unroll
    for (int i = 0; i < NLAYERS * NF4 / THREADS; ++i)
        lW[tid + i * THREADS] = Wv[tid + i * THREADS];

    float4 b0 = bv[0 * NF4 + tid];
    float4 b1 = bv[1 * NF4 + tid];
    float4 b2 = bv[2 * NF4 + tid];
    float4 b3 = bv[3 * NF4 + tid];
    float4 w1 = Wv[1 * NF4 + tid];
    float4 w2 = Wv[2 * NF4 + tid];
    float4 w3 = Wv[3 * NF4 + tid];

    float4 pre = b0;
    float c1 = pre.x * w1.x + pre.y * w1.y + pre.z * w1.z + pre.w * w1.w;
    pre.x += b1.x; pre.y += b1.y; pre.z += b1.z; pre.w += b1.w;
    float c2 = pre.x * w2.x + pre.y * w2.y + pre.z * w2.z + pre.w * w2.w;
    pre.x += b2.x; pre.y += b2.y; pre.z += b2.z; pre.w += b2.w;
    float c3 = pre.x * w3.x + pre.y * w3.y + pre.z * w3.z + pre.w * w3.w;
    pre.x += b3.x; pre.y += b3.y; pre.z += b3.z; pre.w += b3.w;

#pragma unroll
    for (int off = 32; off; off >>= 1) {
        c1 += __shfl_xor(c1, off, 64);
        c2 += __shfl_xor(c2, off, 64);
        c3 += __shfl_xor(c3, off, 64);
    }
    float* scratch = reinterpret_cast<float*>(lBsum);   // overlay, pre-lBsum
    if (lane == 0) { scratch[wv] = c1; scratch[4 + wv] = c2; scratch[8 + wv] = c3; }
    __syncthreads();
    const float cp1 = scratch[0] + scratch[1] + scratch[2]  + scratch[3];
    const float cp2 = scratch[4] + scratch[5] + scratch[6]  + scratch[7];
    const float cp3 = scratch[8] + scratch[9] + scratch[10] + scratch[11];
    __syncthreads();                    // scratch reads done before overwrite
    lBsum[tid] = pre;
    __syncthreads();

    float4 bs[4];
#pragma unroll
    for (int j = 0; j < 4; ++j) bs[j] = lBsum[j * 64 + lane];

    // ---- two rows per wave, interleaved dual reduce chains (R5) ----
    float da[NLAYERS] = {0.f, 0.f, 0.f, 0.f};
    float db[NLAYERS] = {0.f, 0.f, 0.f, 0.f};
#pragma unroll
    for (int j = 0; j < 4; ++j) {
        const int fi = j * 64 + lane;
#pragma unroll
        for (int l = 0; l < NLAYERS; ++l) {
            float4 wl = lW[l * NF4 + fi];
            da[l] += A[j].x * wl.x + A[j].y * wl.y + A[j].z * wl.z + A[j].w * wl.w;
            db[l] += B[j].x * wl.x + B[j].y * wl.y + B[j].z * wl.z + B[j].w * wl.w;
        }
    }

#pragma unroll
    for (int off = 32; off; off >>= 1) {
#pragma unroll
        for (int l = 0; l < NLAYERS; ++l) {
            da[l] += __shfl_xor(da[l], off, 64);
            db[l] += __shfl_xor(db[l], off, 64);
        }
    }

    float alA = 1.0f, alB = 1.0f;
    { float s = alA * da[0];            alA += s;
      s = fmaf(alA, da[1], cp1);        alA += s;
      s = fmaf(alA, da[2], cp2);        alA += s;
      s = fmaf(alA, da[3], cp3);        alA += s; }
    { float s = alB * db[0];            alB += s;
      s = fmaf(alB, db[1], cp1);        alB += s;
      s = fmaf(alB, db[2], cp2);        alB += s;
      s = fmaf(alB, db[3], cp3);        alB += s; }

    floatx4* oa = reinterpret_cast<floatx4*>(out) + r0 * NF4;
    floatx4* ob = reinterpret_cast<floatx4*>(out) + r1 * NF4;
#pragma unroll
    for (int j = 0; j < 4; ++j) {
        floatx4 o;
        o.x = fmaf(alA, A[j].x, bs[j].x);
        o.y = fmaf(alA, A[j].y, bs[j].y);
        o.z = fmaf(alA, A[j].z, bs[j].z);
        o.w = fmaf(alA, A[j].w, bs[j].w);
        __builtin_nontemporal_store(o, &oa[j * 64 + lane]);
    }
#pragma unroll
    for (int j = 0; j < 4; ++j) {
        floatx4 o;
        o.x = fmaf(alB, B[j].x, bs[j].x);
        o.y = fmaf(alB, B[j].y, bs[j].y);
        o.z = fmaf(alB, B[j].z, bs[j].z);
        o.w = fmaf(alB, B[j].w, bs[j].w);
        __builtin_nontemporal_store(o, &ob[j * 64 + lane]);
    }
}

extern "C" void kernel_launch(void* const* d_in, const int* in_sizes, int n_in,
                              void* d_out, int out_size, void* d_ws, size_t ws_size,
                              hipStream_t stream) {
    const float* x0 = (const float*)d_in[0];
    const float* W  = (const float*)d_in[1];
    const float* b  = (const float*)d_in[2];
    float* out      = (float*)d_out;

    crossnet_kernel<<<NBLOCKS, THREADS, 0, stream>>>(x0, W, b, out);
}